// Round 5
// baseline (390.460 us; speedup 1.0000x reference)
//
#include <hip/hip_runtime.h>
#include <math.h>

#define B_    2
#define S_    2048
#define E_    2048
#define H_    32
#define HKV_  8
#define D_    64

typedef __bf16 bf16x8 __attribute__((ext_vector_type(8)));
typedef __bf16 bf16x4 __attribute__((ext_vector_type(4)));
typedef float  f32x4  __attribute__((ext_vector_type(4)));

#define GPTR(x) ((const __attribute__((address_space(1))) void*)(x))
#define LPTR(x) ((__attribute__((address_space(3))) void*)(x))

// ---------------------------------------------------------------------------
// fp32 -> bf16 flat convert (x)
// ---------------------------------------------------------------------------
__global__ __launch_bounds__(256) void convert_kernel(
    const float* __restrict__ in, __bf16* __restrict__ out, int n8)
{
    const int i = blockIdx.x * 256 + threadIdx.x;
    if (i >= n8) return;
    const float4 a = ((const float4*)in)[i * 2];
    const float4 b = ((const float4*)in)[i * 2 + 1];
    bf16x8 o;
    o[0] = (__bf16)a.x; o[1] = (__bf16)a.y; o[2] = (__bf16)a.z; o[3] = (__bf16)a.w;
    o[4] = (__bf16)b.x; o[5] = (__bf16)b.y; o[6] = (__bf16)b.z; o[7] = (__bf16)b.w;
    ((bf16x8*)out)[i] = o;
}

// ---------------------------------------------------------------------------
// fp32 (K,N) row-major -> bf16 (N,K) row-major (B^T for the MFMA GEMM)
// ---------------------------------------------------------------------------
__global__ __launch_bounds__(256) void transpose_convert_kernel(
    const float* __restrict__ in, __bf16* __restrict__ out, int K, int N)
{
    __shared__ float tile[32][33];
    const int k0 = blockIdx.y * 32, n0 = blockIdx.x * 32;
    const int r  = threadIdx.x >> 3;
    const int c4 = (threadIdx.x & 7) * 4;
    const float4 v = *(const float4*)&in[(size_t)(k0 + r) * N + n0 + c4];
    tile[r][c4 + 0] = v.x; tile[r][c4 + 1] = v.y;
    tile[r][c4 + 2] = v.z; tile[r][c4 + 3] = v.w;
    __syncthreads();
    ushort4 o;
    __bf16 h0 = (__bf16)tile[c4 + 0][r]; o.x = __builtin_bit_cast(unsigned short, h0);
    __bf16 h1 = (__bf16)tile[c4 + 1][r]; o.y = __builtin_bit_cast(unsigned short, h1);
    __bf16 h2 = (__bf16)tile[c4 + 2][r]; o.z = __builtin_bit_cast(unsigned short, h2);
    __bf16 h3 = (__bf16)tile[c4 + 3][r]; o.w = __builtin_bit_cast(unsigned short, h3);
    *(ushort4*)&out[(size_t)(n0 + r) * K + k0 + c4] = o;
}

// ---------------------------------------------------------------------------
// bf16 MFMA GEMM body (m97 structure) — unchanged
// ---------------------------------------------------------------------------
__device__ __forceinline__ void gemm_mfma_body(
    const __bf16* __restrict__ A, const __bf16* __restrict__ Bt,
    int m0, int n0, int K, __bf16* sA, __bf16* sB, f32x4 acc[4][4])
{
    const int t    = threadIdx.x;
    const int w    = t >> 6;
    const int lane = t & 63;
    const int col  = lane & 15;
    const int quad = lane >> 4;
    const int wrow = (w >> 1) * 64;
    const int wcol = (w & 1) * 64;

    const int row0 = t >> 3;
    const int c0   = t & 7;

    for (int k0 = 0; k0 < K; k0 += 64) {
#pragma unroll
        for (int it = 0; it < 4; ++it) {
            const int row  = it * 32 + row0;
            const int csrc = c0 ^ (row & 7);
            __builtin_amdgcn_global_load_lds(
                GPTR(A + (size_t)(m0 + row) * K + k0 + csrc * 8),
                LPTR(sA + (it * 256 + t) * 8), 16, 0, 0);
        }
#pragma unroll
        for (int it = 0; it < 4; ++it) {
            const int row  = it * 32 + row0;
            const int csrc = c0 ^ (row & 7);
            __builtin_amdgcn_global_load_lds(
                GPTR(Bt + (size_t)(n0 + row) * K + k0 + csrc * 8),
                LPTR(sB + (it * 256 + t) * 8), 16, 0, 0);
        }
        __syncthreads();

#pragma unroll
        for (int kk = 0; kk < 2; ++kk) {
            bf16x8 af[4], bfr[4];
#pragma unroll
            for (int i = 0; i < 4; ++i) {
                const int m = wrow + i * 16 + col;
                af[i] = *(const bf16x8*)&sA[m * 64 + (((kk * 4 + quad) ^ (m & 7)) * 8)];
            }
#pragma unroll
            for (int j = 0; j < 4; ++j) {
                const int n = wcol + j * 16 + col;
                bfr[j] = *(const bf16x8*)&sB[n * 64 + (((kk * 4 + quad) ^ (n & 7)) * 8)];
            }
#pragma unroll
            for (int i = 0; i < 4; ++i)
#pragma unroll
                for (int j = 0; j < 4; ++j)
                    acc[i][j] = __builtin_amdgcn_mfma_f32_16x16x32_bf16(
                        af[i], bfr[j], acc[i][j], 0, 0, 0);
        }
        __syncthreads();
    }
}

__global__ __launch_bounds__(256) void gemm_qkv_kernel(
    const __bf16* __restrict__ xb, const __bf16* __restrict__ wT,
    __bf16* __restrict__ qb, __bf16* __restrict__ kb, __bf16* __restrict__ vb)
{
    __shared__ __bf16 sA[128 * 64];
    __shared__ __bf16 sB[128 * 64];
    f32x4 acc[4][4];
#pragma unroll
    for (int i = 0; i < 4; ++i)
#pragma unroll
        for (int j = 0; j < 4; ++j) acc[i][j] = (f32x4){0.f, 0.f, 0.f, 0.f};

    const int bx = blockIdx.x;
    const int m0 = blockIdx.y * 128;
    gemm_mfma_body(xb, wT, m0, bx * 128, E_, sA, sB, acc);

    __bf16* Cp; int ldc, nb;
    if (bx < 16)      { Cp = qb; ldc = H_ * D_;   nb = bx * 128; }
    else if (bx < 20) { Cp = kb; ldc = HKV_ * D_; nb = (bx - 16) * 128; }
    else              { Cp = vb; ldc = HKV_ * D_; nb = (bx - 20) * 128; }

    const int lane = threadIdx.x & 63;
    const int col  = lane & 15;
    const int quad = lane >> 4;
    const int wrow = ((threadIdx.x >> 6) >> 1) * 64;
    const int wcol = ((threadIdx.x >> 6) & 1) * 64;
#pragma unroll
    for (int i = 0; i < 4; ++i)
#pragma unroll
        for (int j = 0; j < 4; ++j)
#pragma unroll
            for (int r = 0; r < 4; ++r) {
                const int m = m0 + wrow + i * 16 + quad * 4 + r;
                const int n = nb + wcol + j * 16 + col;
                Cp[(size_t)m * ldc + n] = (__bf16)acc[i][j][r];
            }
}

__global__ __launch_bounds__(256) void gemm_out_kernel(
    const __bf16* __restrict__ ob, const __bf16* __restrict__ woT,
    const float* __restrict__ bias, float* __restrict__ out)
{
    __shared__ __bf16 sA[128 * 64];
    __shared__ __bf16 sB[128 * 64];
    f32x4 acc[4][4];
#pragma unroll
    for (int i = 0; i < 4; ++i)
#pragma unroll
        for (int j = 0; j < 4; ++j) acc[i][j] = (f32x4){0.f, 0.f, 0.f, 0.f};

    const int m0 = blockIdx.y * 128;
    const int n0 = blockIdx.x * 128;
    gemm_mfma_body(ob, woT, m0, n0, H_ * D_, sA, sB, acc);

    const int lane = threadIdx.x & 63;
    const int col  = lane & 15;
    const int quad = lane >> 4;
    const int wrow = ((threadIdx.x >> 6) >> 1) * 64;
    const int wcol = ((threadIdx.x >> 6) & 1) * 64;
#pragma unroll
    for (int i = 0; i < 4; ++i)
#pragma unroll
        for (int j = 0; j < 4; ++j)
#pragma unroll
            for (int r = 0; r < 4; ++r) {
                const int m = m0 + wrow + i * 16 + quad * 4 + r;
                const int n = n0 + wcol + j * 16 + col;
                out[(size_t)m * E_ + n] = acc[i][j][r] + bias[n];
            }
}

// ---------------------------------------------------------------------------
// RoPE (unchanged)
// ---------------------------------------------------------------------------
__global__ __launch_bounds__(256) void rope_kernel(
    __bf16* __restrict__ p, const float* __restrict__ fc,
    const float* __restrict__ fs, int nh, int npairs)
{
    const int i = blockIdx.x * 256 + threadIdx.x;
    if (i >= npairs) return;
    const int pair = i & 31;
    const int row  = i >> 5;
    const int s    = (row / nh) % S_;
    const unsigned int v = ((const unsigned int*)p)[i];
    const float x0 = (float)__builtin_bit_cast(__bf16, (unsigned short)(v & 0xffff));
    const float x1 = (float)__builtin_bit_cast(__bf16, (unsigned short)(v >> 16));
    const float c  = fc[s * 32 + pair];
    const float sn = fs[s * 32 + pair];
    const __bf16 r0 = (__bf16)(x0 * c - x1 * sn);
    const __bf16 r1 = (__bf16)(x0 * sn + x1 * c);
    ((unsigned int*)p)[i] =
        ((unsigned int)__builtin_bit_cast(unsigned short, r1) << 16) |
        (unsigned int)__builtin_bit_cast(unsigned short, r0);
}

// ---------------------------------------------------------------------------
// MFMA flash attention v3: 64 q-rows/wave, 32-key PV halves, swizzled sP.
// sP[wave][64 q][32 keys] bf16, no pad; 8B-granule XOR swizzle
//   g' = g ^ (row&7) ^ ((row>>3)&1)   (row = q index in wave tile)
// -> b64 P-writes and b64 P-reads are perfect 16-granule permutations per
//    16-lane phase = conflict-free. Q pre-scaled by 1/8 (exact).
// ---------------------------------------------------------------------------
__global__ __launch_bounds__(256, 2) void attn_kernel(
    const __bf16* __restrict__ qw, const __bf16* __restrict__ kw,
    const __bf16* __restrict__ vw, __bf16* __restrict__ ow)
{
    __shared__ __bf16 sK [64][72];
    __shared__ __bf16 sVT[64][72];
    __shared__ __bf16 sP [4][64][32];   // per-wave, swizzled

    const int t    = threadIdx.x;
    const int w    = t >> 6;
    const int lane = t & 63;
    const int col  = lane & 15;
    const int quad = lane >> 4;
    const int sw   = (col & 7) ^ ((col >> 3) & 1);   // row-swizzle (row≡col mod 16)

    const int bh  = blockIdx.y;
    const int b   = bh >> 5;
    const int h   = bh & 31;
    const int kvh = h >> 2;
    const int q0w = blockIdx.x * 256 + w * 64;

    const int KSTR = HKV_ * D_;   // 512 elements

    // Q fragments pre-scaled by 0.125 (exact power of 2)
    bf16x8 bQ[4][2];
#pragma unroll
    for (int qf = 0; qf < 4; ++qf) {
        const __bf16* qrow = qw + (((size_t)b * S_ + q0w + qf * 16 + col) * H_ + h) * D_;
        bf16x8 r0 = ((const bf16x8*)qrow)[quad];
        bf16x8 r1 = ((const bf16x8*)qrow)[4 + quad];
#pragma unroll
        for (int e = 0; e < 8; ++e) {
            r0[e] = (__bf16)((float)r0[e] * 0.125f);
            r1[e] = (__bf16)((float)r1[e] * 0.125f);
        }
        bQ[qf][0] = r0;
        bQ[qf][1] = r1;
    }

    f32x4 O[4][4];
#pragma unroll
    for (int qf = 0; qf < 4; ++qf)
#pragma unroll
        for (int dt = 0; dt < 4; ++dt) O[qf][dt] = (f32x4){0.f, 0.f, 0.f, 0.f};
    float lr[4] = {0.f, 0.f, 0.f, 0.f};

    const __bf16* kbase = kw + ((size_t)b * S_ * HKV_ + kvh) * D_;
    const __bf16* vbase = vw + ((size_t)b * S_ * HKV_ + kvh) * D_;

    const int kkey = t >> 2;
    const int kd   = (t & 3) * 16;
    const int vkp  = (t & 31) * 2;
    const int vdg  = (t >> 5) * 4;

    for (int j0 = 0; j0 < S_; j0 += 64) {
        // ---- stage K [key][dim]
        {
            const __bf16* kr = kbase + (size_t)(j0 + kkey) * KSTR + kd;
            *(bf16x8*)&sK[kkey][kd]     = ((const bf16x8*)kr)[0];
            *(bf16x8*)&sK[kkey][kd + 8] = ((const bf16x8*)kr)[1];
        }
        // ---- stage V transposed [dim][key]
#pragma unroll
        for (int r = 0; r < 64; r += 32) {
            const __bf16* v0 = vbase + (size_t)(j0 + vkp) * KSTR + vdg + r;
            const __bf16* v1 = v0 + KSTR;
            const ushort4 ua = *(const ushort4*)v0;
            const ushort4 uc = *(const ushort4*)v1;
            *(unsigned int*)&sVT[vdg + r + 0][vkp] = ((unsigned int)uc.x << 16) | ua.x;
            *(unsigned int*)&sVT[vdg + r + 1][vkp] = ((unsigned int)uc.y << 16) | ua.y;
            *(unsigned int*)&sVT[vdg + r + 2][vkp] = ((unsigned int)uc.z << 16) | ua.z;
            *(unsigned int*)&sVT[vdg + r + 3][vkp] = ((unsigned int)uc.w << 16) | ua.w;
        }
        __syncthreads();

#pragma unroll
        for (int half = 0; half < 2; ++half) {
            // ---- QK^T for this half's 32 keys (2 subtiles of 16)
#pragma unroll
            for (int sti = 0; sti < 2; ++sti) {
                const int st = half * 2 + sti;
                const bf16x8 aK0 = *(const bf16x8*)&sK[st * 16 + col][quad * 8];
                const bf16x8 aK1 = *(const bf16x8*)&sK[st * 16 + col][32 + quad * 8];
#pragma unroll
                for (int qf = 0; qf < 4; ++qf) {
                    f32x4 sc = (f32x4){0.f, 0.f, 0.f, 0.f};
                    sc = __builtin_amdgcn_mfma_f32_16x16x32_bf16(aK0, bQ[qf][0], sc, 0, 0, 0);
                    sc = __builtin_amdgcn_mfma_f32_16x16x32_bf16(aK1, bQ[qf][1], sc, 0, 0, 0);
                    bf16x4 pk;
                    float psum = 0.f;
#pragma unroll
                    for (int r = 0; r < 4; ++r) {
                        const float p = __expf(sc[r]);
                        psum += p;
                        pk[r] = (__bf16)p;
                    }
                    lr[qf] += psum;
                    // write granule g = sti*4+quad (key-in-half / 4), swizzled
                    const int gs = (sti * 4 + quad) ^ sw;
                    *(bf16x4*)&sP[w][qf * 16 + col][gs * 4] = pk;
                }
            }

            // ---- PV for this half: A = P (swizzled b64 pairs), B = V^T
            bf16x8 vbf[4];
#pragma unroll
            for (int dt = 0; dt < 4; ++dt)
                vbf[dt] = *(const bf16x8*)&sVT[dt * 16 + col][half * 32 + quad * 8];
#pragma unroll
            for (int qf = 0; qf < 4; ++qf) {
                const int gs0 = (2 * quad)     ^ sw;
                const int gs1 = (2 * quad + 1) ^ sw;
                const bf16x4 lo = *(const bf16x4*)&sP[w][qf * 16 + col][gs0 * 4];
                const bf16x4 hi = *(const bf16x4*)&sP[w][qf * 16 + col][gs1 * 4];
                bf16x8 pa;
                pa[0] = lo[0]; pa[1] = lo[1]; pa[2] = lo[2]; pa[3] = lo[3];
                pa[4] = hi[0]; pa[5] = hi[1]; pa[6] = hi[2]; pa[7] = hi[3];
#pragma unroll
                for (int dt = 0; dt < 4; ++dt)
                    O[qf][dt] = __builtin_amdgcn_mfma_f32_16x16x32_bf16(
                        pa, vbf[dt], O[qf][dt], 0, 0, 0);
            }
        }
        __syncthreads();
    }

    // ---- l reduce over quads (keys were distributed across quads)
#pragma unroll
    for (int qf = 0; qf < 4; ++qf) {
        lr[qf] += __shfl_xor(lr[qf], 16);
        lr[qf] += __shfl_xor(lr[qf], 32);
    }

    // ---- O epilogue: C-layout row = quad*4+r, col = d-in-tile
#pragma unroll
    for (int qf = 0; qf < 4; ++qf)
#pragma unroll
        for (int r = 0; r < 4; ++r) {
            const float lv  = __shfl(lr[qf], quad * 4 + r);
            const float inv = 1.f / lv;
            const int   qr  = q0w + qf * 16 + quad * 4 + r;
            __bf16* orow = ow + (((size_t)b * S_ + qr) * H_ + h) * D_;
#pragma unroll
            for (int dt = 0; dt < 4; ++dt)
                orow[dt * 16 + col] = (__bf16)(O[qf][dt][r] * inv);
        }
}

// ---------------------------------------------------------------------------
extern "C" void kernel_launch(void* const* d_in, const int* in_sizes, int n_in,
                              void* d_out, int out_size, void* d_ws, size_t ws_size,
                              hipStream_t stream)
{
    const float* x  = (const float*)d_in[0];
    const float* fc = (const float*)d_in[2];
    const float* fs = (const float*)d_in[3];
    const float* wq = (const float*)d_in[4];
    const float* wk = (const float*)d_in[5];
    const float* wv = (const float*)d_in[6];
    const float* wo = (const float*)d_in[7];
    const float* obias = (const float*)d_in[8];
    float* out = (float*)d_out;

    __bf16* ws  = (__bf16*)d_ws;
    __bf16* xb  = ws;                                    // 4096*2048
    __bf16* wT  = xb  + (size_t)4096 * 2048;             // 3072*2048 [wq^T|wk^T|wv^T]
    __bf16* woT = wT  + (size_t)3072 * 2048;             // 2048*2048
    __bf16* qb  = woT + (size_t)2048 * 2048;             // B,S,H,D
    __bf16* kb  = qb  + (size_t)B_ * S_ * H_ * D_;       // B,S,HKV,D
    __bf16* vb  = kb  + (size_t)B_ * S_ * HKV_ * D_;
    __bf16* obf = vb  + (size_t)B_ * S_ * HKV_ * D_;     // B,S,H,D

    convert_kernel<<<4096, 256, 0, stream>>>(x, xb, 4096 * 2048 / 8);
    transpose_convert_kernel<<<dim3(64, 64), 256, 0, stream>>>(wq, wT, E_, 2048);
    transpose_convert_kernel<<<dim3(16, 64), 256, 0, stream>>>(wk, wT + (size_t)2048 * 2048, E_, 512);
    transpose_convert_kernel<<<dim3(16, 64), 256, 0, stream>>>(wv, wT + (size_t)2560 * 2048, E_, 512);
    transpose_convert_kernel<<<dim3(64, 64), 256, 0, stream>>>(wo, woT, H_ * D_, E_);

    gemm_qkv_kernel<<<dim3(24, 32), 256, 0, stream>>>(xb, wT, qb, kb, vb);

    rope_kernel<<<(B_ * S_ * H_ * 32 + 255) / 256, 256, 0, stream>>>(
        qb, fc, fs, H_, B_ * S_ * H_ * 32);
    rope_kernel<<<(B_ * S_ * HKV_ * 32 + 255) / 256, 256, 0, stream>>>(
        kb, fc, fs, HKV_, B_ * S_ * HKV_ * 32);

    attn_kernel<<<dim3(S_ / 256, B_ * H_), 256, 0, stream>>>(qb, kb, vb, obf);

    gemm_out_kernel<<<dim3(16, 32), 256, 0, stream>>>(obf, woT, obias, out);
}